// Round 4
// baseline (895.811 us; speedup 1.0000x reference)
//
#include <hip/hip_runtime.h>
#include <hip/hip_bf16.h>
#include <stdint.h>

// ---------------------------------------------------------------------------
// Bahdanau additive attention, B=32, T=2048, D=U=1024. fp32 in/out.
// Outputs (fp32, flat): ctx [32*1024] then weights [32*2048].
// Score GEMM: barrier-free, LDS-free, direct-from-L2 MFMA with register
// double-buffering (values pre-converted to bf16; W2T bf16, L2-resident).
// ---------------------------------------------------------------------------

typedef unsigned short ushort_t;
typedef short bf16x8 __attribute__((ext_vector_type(8)));
typedef float f32x4 __attribute__((ext_vector_type(4)));

__device__ __forceinline__ float bf2f(ushort_t h) {
    union { unsigned int u; float f; } v;
    v.u = ((unsigned int)h) << 16;
    return v.f;
}
__device__ __forceinline__ ushort_t f2bf(float f) {
    union { float f; unsigned int u; } v;
    v.f = f;
    unsigned int u = v.u;
    unsigned int r = u + 0x7FFFu + ((u >> 16) & 1u);  // RNE
    return (ushort_t)(r >> 16);
}
__device__ __forceinline__ unsigned int pk2(float a, float b) {
    union { __hip_bfloat162 h; unsigned int u; } c;
    c.h = __float22bfloat162_rn(make_float2(a, b));  // v_cvt_pk_bf16_f32
    return c.u;
}
__device__ __forceinline__ float fast_tanh(float x) {
    float ax = __builtin_fabsf(x);
    float e = __expf(-2.0f * ax);
    float t = (1.0f - e) * __builtin_amdgcn_rcpf(1.0f + e);
    return __builtin_copysignf(t, x);
}

static constexpr int B_ = 32, T_ = 2048, D_ = 1024, U_ = 1024;
static constexpr int M_ = B_ * T_;  // 65536
static constexpr int CONV_B = M_ * D_ / (256 * 8);  // 32768
static constexpr int TRANS_B = 1024;
static constexpr int QPROJ_B = 512;

// ---------------- kernel 1: fused prep (convert | transpose | qproj) -------
__global__ __launch_bounds__(256) void k_prep(const float* __restrict__ values,
                                              const float* __restrict__ W2,
                                              const float* __restrict__ query,
                                              const float* __restrict__ W1,
                                              const float* __restrict__ b1,
                                              const float* __restrict__ b2,
                                              ushort_t* __restrict__ Vbf,
                                              ushort_t* __restrict__ W2T,
                                              float* __restrict__ qpb,
                                              int conv_blocks) {
    __shared__ float smem[1280];
    int bid = blockIdx.x;
    const int tid = threadIdx.x;

    if (bid < conv_blocks) {  // values fp32 -> bf16
        size_t i = ((size_t)bid * 256 + tid) * 8;
        f32x4 a = *(const f32x4*)(values + i);
        f32x4 b = *(const f32x4*)(values + i + 4);
        uint4 p;
        p.x = pk2(a[0], a[1]);
        p.y = pk2(a[2], a[3]);
        p.z = pk2(b[0], b[1]);
        p.w = pk2(b[2], b[3]);
        *(uint4*)(Vbf + i) = p;
        return;
    }
    bid -= conv_blocks;

    if (bid < TRANS_B) {  // W2 [D][U] -> W2T [U][D] bf16
        float(*tile)[33] = (float(*)[33])smem;
        int u0 = (bid & 31) * 32, d0 = (bid >> 5) * 32;
        int tx = tid & 31, ty = tid >> 5;
#pragma unroll
        for (int r = 0; r < 4; ++r)
            tile[ty + r * 8][tx] = W2[(size_t)(d0 + ty + r * 8) * U_ + (u0 + tx)];
        __syncthreads();
#pragma unroll
        for (int r = 0; r < 4; ++r)
            W2T[(size_t)(u0 + ty + r * 8) * D_ + (d0 + tx)] = f2bf(tile[tx][ty + r * 8]);
        return;
    }
    bid -= TRANS_B;

    // qproj: qpb[b][u] = query[b]@W1[:,u] + b1[u] + b2[u]
    const int b = bid >> 4, uc = bid & 15;
    float* qs = smem;          // [1024]
    float* red = smem + 1024;  // [256]
    for (int i = tid; i < D_; i += 256) qs[i] = query[b * D_ + i];
    __syncthreads();
    const int ul = tid & 63, ds = tid >> 6;
    const int u = uc * 64 + ul;
    float acc = 0.f;
#pragma unroll 8
    for (int d = ds * 256; d < ds * 256 + 256; ++d)
        acc += qs[d] * W1[(size_t)d * U_ + u];
    red[tid] = acc;
    __syncthreads();
    if (tid < 64) {
        int uu = uc * 64 + tid;
        qpb[b * U_ + uu] = red[tid] + red[tid + 64] + red[tid + 128] + red[tid + 192] +
                           b1[uu] + b2[uu];
    }
}

// ---------------- kernel 2: barrier-free fused GEMM + tanh + Wv-dot --------
#define BM 128
#define BN 128

__global__ __launch_bounds__(256, 3) void k_score_gemm(const ushort_t* __restrict__ Vbf,
                                                       const ushort_t* __restrict__ W2T,
                                                       const float* __restrict__ qpb,
                                                       const float* __restrict__ Wv,
                                                       float* __restrict__ scores_partial) {
    __shared__ float sScore[BM];

    const int tid = threadIdx.x;
    const int lane = tid & 63;
    const int w = tid >> 6;
    const int wm = w >> 1, wn = w & 1;
    const int quad = lane >> 4, l15 = lane & 15;

    // XCD-grouped order: all 8 n-blocks of an m-tile land on one XCD
    const int g = blockIdx.x;
    const int mt = ((g >> 6) << 3) | (g & 7);
    const int nt = (g >> 3) & 7;
    const int m0 = mt * BM, n0 = nt * BN;

    if (tid < BM) sScore[tid] = 0.f;
    __syncthreads();

    f32x4 acc[4][4];
#pragma unroll
    for (int i = 0; i < 4; ++i)
#pragma unroll
        for (int j = 0; j < 4; ++j) acc[i][j] = (f32x4){0.f, 0.f, 0.f, 0.f};

    // fragment sources: A row = m0+wm*64+i*16+l15, B row = n0+wn*64+j*16+l15,
    // cols = k0 + quad*8 .. +7 (16x16x32 A/B operand layout)
    const ushort_t* aBase = Vbf + (size_t)(m0 + wm * 64 + l15) * D_ + quad * 8;
    const ushort_t* bBase = W2T + (size_t)(n0 + wn * 64 + l15) * D_ + quad * 8;

    bf16x8 a0[4], b0[4], a1[4], b1[4];
#pragma unroll
    for (int i = 0; i < 4; ++i) a0[i] = *(const bf16x8*)(aBase + i * 16 * D_);
#pragma unroll
    for (int j = 0; j < 4; ++j) b0[j] = *(const bf16x8*)(bBase + j * 16 * D_);

    for (int k0 = 0; k0 < D_; k0 += 64) {
        const int k1 = k0 + 32;
#pragma unroll
        for (int i = 0; i < 4; ++i) a1[i] = *(const bf16x8*)(aBase + k1 + i * 16 * D_);
#pragma unroll
        for (int j = 0; j < 4; ++j) b1[j] = *(const bf16x8*)(bBase + k1 + j * 16 * D_);
#pragma unroll
        for (int i = 0; i < 4; ++i)
#pragma unroll
            for (int j = 0; j < 4; ++j)
                acc[i][j] = __builtin_amdgcn_mfma_f32_16x16x32_bf16(a0[i], b0[j],
                                                                    acc[i][j], 0, 0, 0);
        const int k2 = (k0 + 64) & (D_ - 1);  // last iter wraps (harmless)
#pragma unroll
        for (int i = 0; i < 4; ++i) a0[i] = *(const bf16x8*)(aBase + k2 + i * 16 * D_);
#pragma unroll
        for (int j = 0; j < 4; ++j) b0[j] = *(const bf16x8*)(bBase + k2 + j * 16 * D_);
#pragma unroll
        for (int i = 0; i < 4; ++i)
#pragma unroll
            for (int j = 0; j < 4; ++j)
                acc[i][j] = __builtin_amdgcn_mfma_f32_16x16x32_bf16(a1[i], b1[j],
                                                                    acc[i][j], 0, 0, 0);
    }

    // epilogue: C row = wm*64+i*16+quad*4+r, col(u) = n0+wn*64+j*16+l15
    const int b = m0 >> 11;
    const float* qp = qpb + b * U_;
    float qv[4], wv[4];
#pragma unroll
    for (int j = 0; j < 4; ++j) {
        int u = n0 + wn * 64 + j * 16 + l15;
        qv[j] = qp[u];
        wv[j] = Wv[u];
    }
#pragma unroll
    for (int i = 0; i < 4; ++i) {
#pragma unroll
        for (int r = 0; r < 4; ++r) {
            float s = 0.f;
#pragma unroll
            for (int j = 0; j < 4; ++j) s += fast_tanh(acc[i][j][r] + qv[j]) * wv[j];
            s += __shfl_xor(s, 1);
            s += __shfl_xor(s, 2);
            s += __shfl_xor(s, 4);
            s += __shfl_xor(s, 8);
            if (l15 == 0) atomicAdd(&sScore[wm * 64 + i * 16 + quad * 4 + r], s);
        }
    }
    __syncthreads();
    if (tid < BM) scores_partial[(size_t)(m0 + tid) * 8 + nt] = sScore[tid];
}

// ------- kernel 2b (fallback, ws too small): fp32-A LDS GEMM ---------------
#define BK 64
#define GLOBAL_AS __attribute__((address_space(1)))
#define LDS_AS    __attribute__((address_space(3)))

__global__ __launch_bounds__(256) void k_score_gemm_f32(const float* __restrict__ values,
                                                        const ushort_t* __restrict__ W2T,
                                                        const float* __restrict__ qpb,
                                                        const float* __restrict__ Wv,
                                                        float* __restrict__ scores_partial) {
    __shared__ ushort_t As[BM * BK];
    __shared__ ushort_t Bs[BN * BK];
    __shared__ float sScore[BM];

    const int tid = threadIdx.x;
    const int lane = tid & 63;
    const int w = tid >> 6;
    const int wm = w >> 1, wn = w & 1;
    const int n0 = blockIdx.x * BN;
    const int m0 = blockIdx.y * BM;

    if (tid < BM) sScore[tid] = 0.f;

    f32x4 acc[4][4];
#pragma unroll
    for (int i = 0; i < 4; ++i)
#pragma unroll
        for (int j = 0; j < 4; ++j) acc[i][j] = (f32x4){0.f, 0.f, 0.f, 0.f};

    const int rr = tid >> 4;
    const int cc = tid & 15;
    const float* aSrc = values + (size_t)(m0 + rr) * D_ + cc * 4;
    ushort_t* aDst = As + rr * BK + cc * 4;

    const int mB = lane >> 3;
    const int kB = (lane & 7) * 8;
    const ushort_t* bBase = W2T + (size_t)(n0 + w * 8 + mB) * D_ + kB;

    const int quad = lane >> 4;
    const int l15 = lane & 15;

    for (int k0 = 0; k0 < D_; k0 += BK) {
#pragma unroll
        for (int i = 0; i < 4; ++i) {
            __builtin_amdgcn_global_load_lds(
                (const GLOBAL_AS void*)(bBase + k0 + (size_t)i * 32 * D_),
                (LDS_AS void*)(Bs + i * 2048 + w * 512), 16, 0, 0);
        }
#pragma unroll
        for (int i = 0; i < 8; ++i) {
            f32x4 v = *(const f32x4*)(aSrc + k0 + (size_t)i * 16 * D_);
            uint2 p;
            p.x = pk2(v[0], v[1]);
            p.y = pk2(v[2], v[3]);
            *(uint2*)(aDst + i * 16 * BK) = p;
        }
        __syncthreads();
#pragma unroll
        for (int kk = 0; kk < BK; kk += 32) {
            bf16x8 af[4], bfr[4];
            const int col = kk + quad * 8;
#pragma unroll
            for (int i = 0; i < 4; ++i)
                af[i] = *(const bf16x8*)(As + (wm * 64 + i * 16 + l15) * BK + col);
#pragma unroll
            for (int j = 0; j < 4; ++j)
                bfr[j] = *(const bf16x8*)(Bs + (wn * 64 + j * 16 + l15) * BK + col);
#pragma unroll
            for (int i = 0; i < 4; ++i)
#pragma unroll
                for (int j = 0; j < 4; ++j)
                    acc[i][j] = __builtin_amdgcn_mfma_f32_16x16x32_bf16(
                        af[i], bfr[j], acc[i][j], 0, 0, 0);
        }
        __syncthreads();
    }

    const int b = m0 >> 11;
    const float* qp = qpb + b * U_;
    float qv[4], wv[4];
#pragma unroll
    for (int j = 0; j < 4; ++j) {
        int u = n0 + wn * 64 + j * 16 + l15;
        qv[j] = qp[u];
        wv[j] = Wv[u];
    }
#pragma unroll
    for (int i = 0; i < 4; ++i) {
#pragma unroll
        for (int r = 0; r < 4; ++r) {
            float s = 0.f;
#pragma unroll
            for (int j = 0; j < 4; ++j) s += fast_tanh(acc[i][j][r] + qv[j]) * wv[j];
            s += __shfl_xor(s, 1);
            s += __shfl_xor(s, 2);
            s += __shfl_xor(s, 4);
            s += __shfl_xor(s, 8);
            if (l15 == 0) atomicAdd(&sScore[wm * 64 + i * 16 + quad * 4 + r], s);
        }
    }
    __syncthreads();
    if (tid < BM) scores_partial[(size_t)(m0 + tid) * 8 + blockIdx.x] = sScore[tid];
}

// ---------------- kernel 3: softmax over T per batch -----------------------
__global__ __launch_bounds__(256) void k_softmax(const float* __restrict__ scores_partial,
                                                 const float* __restrict__ bv,
                                                 float* __restrict__ w_f,
                                                 float* __restrict__ out_w) {
    const int b = blockIdx.x;
    __shared__ float s[T_];
    __shared__ float red[4];
    const int tid = threadIdx.x;
    const float bvf = bv[0];

    float lmax = -1e30f;
    for (int t = tid; t < T_; t += 256) {
        const float* p = scores_partial + (size_t)(b * T_ + t) * 8;
        float sc = ((p[0] + p[1]) + (p[2] + p[3])) + ((p[4] + p[5]) + (p[6] + p[7])) + bvf;
        s[t] = sc;
        lmax = fmaxf(lmax, sc);
    }
    for (int off = 32; off; off >>= 1) lmax = fmaxf(lmax, __shfl_xor(lmax, off));
    if ((tid & 63) == 0) red[tid >> 6] = lmax;
    __syncthreads();
    const float gmax = fmaxf(fmaxf(red[0], red[1]), fmaxf(red[2], red[3]));

    float lsum = 0.f;
    for (int t = tid; t < T_; t += 256) {
        float e = __expf(s[t] - gmax);
        s[t] = e;
        lsum += e;
    }
    for (int off = 32; off; off >>= 1) lsum += __shfl_xor(lsum, off);
    __syncthreads();
    if ((tid & 63) == 0) red[tid >> 6] = lsum;
    __syncthreads();
    const float ginv = 1.f / ((red[0] + red[1]) + (red[2] + red[3]));

    for (int t = tid; t < T_; t += 256) {
        float wgt = s[t] * ginv;
        w_f[b * T_ + t] = wgt;
        out_w[b * T_ + t] = wgt;
    }
}

// ---------------- kernel 4: ctx partials (bf16 values) ---------------------
__global__ __launch_bounds__(256) void k_ctx_partial_bf(const ushort_t* __restrict__ Vbf,
                                                        const float* __restrict__ w_f,
                                                        float* __restrict__ ctx_partial) {
    const int tc = blockIdx.x;  // 0..15
    const int b = blockIdx.y;   // 0..31
    const int tid = threadIdx.x;
    __shared__ float wls[128];
    __shared__ float racc[128 * 8];
    if (tid < 128) wls[tid] = w_f[b * T_ + tc * 128 + tid];
    __syncthreads();

    const int dg = tid & 127, th = tid >> 7;
    const int d0 = dg * 8;
    float acc[8] = {0.f, 0.f, 0.f, 0.f, 0.f, 0.f, 0.f, 0.f};
    const ushort_t* base = Vbf + (size_t)(b * T_ + tc * 128) * D_ + d0;
    for (int tt = th; tt < 128; tt += 2) {
        const float wgt = wls[tt];
        bf16x8 v = *(const bf16x8*)(base + (size_t)tt * D_);
#pragma unroll
        for (int i = 0; i < 8; ++i) acc[i] += wgt * bf2f((ushort_t)v[i]);
    }
    if (th == 1) {
#pragma unroll
        for (int i = 0; i < 8; ++i) racc[dg * 8 + i] = acc[i];
    }
    __syncthreads();
    if (th == 0) {
#pragma unroll
        for (int i = 0; i < 8; ++i) acc[i] += racc[dg * 8 + i];
        float* out = ctx_partial + (size_t)(b * 16 + tc) * D_ + d0;
        *(f32x4*)out = (f32x4){acc[0], acc[1], acc[2], acc[3]};
        *(f32x4*)(out + 4) = (f32x4){acc[4], acc[5], acc[6], acc[7]};
    }
}

// ---------------- kernel 4b (fallback): ctx partials (fp32 values) ---------
__global__ __launch_bounds__(256) void k_ctx_partial_f32(const float* __restrict__ values,
                                                         const float* __restrict__ w_f,
                                                         float* __restrict__ ctx_partial) {
    const int tc = blockIdx.x;  // 0..15
    const int b = blockIdx.y;
    const int tid = threadIdx.x;
    __shared__ float wls[128];
    if (tid < 128) wls[tid] = w_f[b * T_ + tc * 128 + tid];
    __syncthreads();

    f32x4 acc = (f32x4){0.f, 0.f, 0.f, 0.f};
    const float* base = values + (size_t)(b * T_ + tc * 128) * D_ + tid * 4;
#pragma unroll 4
    for (int tt = 0; tt < 128; ++tt)
        acc += wls[tt] * *(const f32x4*)(base + (size_t)tt * D_);
    *(f32x4*)(ctx_partial + (size_t)(b * 16 + tc) * D_ + tid * 4) = acc;
}

// ---------------- kernel 5: reduce 16 partials -----------------------------
__global__ __launch_bounds__(256) void k_ctx_reduce(const float* __restrict__ ctx_partial,
                                                    float* __restrict__ out_ctx) {
    const int b = blockIdx.x;
    const int d = blockIdx.y * 256 + threadIdx.x;
    float s = 0.f;
#pragma unroll
    for (int p = 0; p < 16; ++p) s += ctx_partial[(size_t)(b * 16 + p) * D_ + d];
    out_ctx[b * D_ + d] = s;
}

// ---------------------------------------------------------------------------
extern "C" void kernel_launch(void* const* d_in, const int* in_sizes, int n_in,
                              void* d_out, int out_size, void* d_ws, size_t ws_size,
                              hipStream_t stream) {
    const float* query  = (const float*)d_in[0];
    const float* values = (const float*)d_in[1];
    const float* W1     = (const float*)d_in[2];
    const float* b1     = (const float*)d_in[3];
    const float* W2     = (const float*)d_in[4];
    const float* b2     = (const float*)d_in[5];
    const float* Wv     = (const float*)d_in[6];
    const float* bv     = (const float*)d_in[7];

    float* out_ctx = (float*)d_out;          // [32*1024]
    float* out_w   = out_ctx + B_ * D_;      // [32*2048]

    char* ws = (char*)d_ws;
    const size_t OFF_W2T = 0;                 // 2 MB bf16
    const size_t OFF_QPB = 0x200000;          // 128 KB
    const size_t OFF_SP  = 0x220000;          // 2 MB
    const size_t OFF_WF  = 0x420000;          // 256 KB
    const size_t OFF_CP  = 0x460000;          // 2 MB
    const size_t OFF_VBF = 0x660000;          // 128 MB bf16 values
    const size_t NEED    = OFF_VBF + (size_t)M_ * D_ * sizeof(ushort_t);

    ushort_t* W2T            = (ushort_t*)(ws + OFF_W2T);
    float*    qpb            = (float*)(ws + OFF_QPB);
    float*    scores_partial = (float*)(ws + OFF_SP);
    float*    w_f            = (float*)(ws + OFF_WF);
    float*    ctx_partial    = (float*)(ws + OFF_CP);
    ushort_t* Vbf            = (ushort_t*)(ws + OFF_VBF);

    if (ws_size >= NEED) {
        k_prep<<<dim3(CONV_B + TRANS_B + QPROJ_B), 256, 0, stream>>>(
            values, W2, query, W1, b1, b2, Vbf, W2T, qpb, CONV_B);
        k_score_gemm<<<dim3((M_ / BM) * (U_ / BN)), 256, 0, stream>>>(
            Vbf, W2T, qpb, Wv, scores_partial);
        k_softmax<<<dim3(B_), 256, 0, stream>>>(scores_partial, bv, w_f, out_w);
        k_ctx_partial_bf<<<dim3(16, B_), 256, 0, stream>>>(Vbf, w_f, ctx_partial);
    } else {
        k_prep<<<dim3(TRANS_B + QPROJ_B), 256, 0, stream>>>(
            values, W2, query, W1, b1, b2, Vbf, W2T, qpb, 0);
        k_score_gemm_f32<<<dim3(U_ / BN, M_ / BM), 256, 0, stream>>>(
            values, W2T, qpb, Wv, scores_partial);
        k_softmax<<<dim3(B_), 256, 0, stream>>>(scores_partial, bv, w_f, out_w);
        k_ctx_partial_f32<<<dim3(16, B_), 256, 0, stream>>>(values, w_f, ctx_partial);
    }
    k_ctx_reduce<<<dim3(B_, D_ / 256), 256, 0, stream>>>(ctx_partial, out_ctx);

    (void)in_sizes; (void)n_in; (void)out_size; (void)ws_size;
}

// Round 5
// 629.745 us; speedup vs baseline: 1.4225x; 1.4225x over previous
//
#include <hip/hip_runtime.h>
#include <hip/hip_bf16.h>
#include <stdint.h>

// ---------------------------------------------------------------------------
// Bahdanau additive attention, B=32, T=2048, D=U=1024. fp32 in/out.
// Outputs (fp32, flat): ctx [32*1024] then weights [32*2048].
// GEMM: LDS-staged bf16 MFMA (global_load_lds w=16, XOR swizzle, XCD-grouped
// block order) — round-3 verified structure. values pre-converted to bf16.
// ---------------------------------------------------------------------------

typedef unsigned short ushort_t;
typedef short bf16x8 __attribute__((ext_vector_type(8)));
typedef float f32x4 __attribute__((ext_vector_type(4)));

#define GLOBAL_AS __attribute__((address_space(1)))
#define LDS_AS    __attribute__((address_space(3)))

__device__ __forceinline__ float bf2f(ushort_t h) {
    union { unsigned int u; float f; } v;
    v.u = ((unsigned int)h) << 16;
    return v.f;
}
__device__ __forceinline__ ushort_t f2bf(float f) {
    union { float f; unsigned int u; } v;
    v.f = f;
    unsigned int u = v.u;
    unsigned int r = u + 0x7FFFu + ((u >> 16) & 1u);  // RNE
    return (ushort_t)(r >> 16);
}
__device__ __forceinline__ unsigned int pk2(float a, float b) {
    union { __hip_bfloat162 h; unsigned int u; } c;
    c.h = __float22bfloat162_rn(make_float2(a, b));  // v_cvt_pk_bf16_f32
    return c.u;
}
__device__ __forceinline__ float fast_tanh(float x) {
    float ax = __builtin_fabsf(x);
    float e = __expf(-2.0f * ax);
    float t = (1.0f - e) * __builtin_amdgcn_rcpf(1.0f + e);
    return __builtin_copysignf(t, x);
}

static constexpr int B_ = 32, T_ = 2048, D_ = 1024, U_ = 1024;
static constexpr int M_ = B_ * T_;  // 65536
static constexpr int CONV_B = M_ * D_ / (256 * 8);  // 32768
static constexpr int TRANS_B = 1024;
static constexpr int QPROJ_B = 512;

// ---------------- kernel 1: fused prep (convert | transpose | qproj) -------
__global__ __launch_bounds__(256) void k_prep(const float* __restrict__ values,
                                              const float* __restrict__ W2,
                                              const float* __restrict__ query,
                                              const float* __restrict__ W1,
                                              const float* __restrict__ b1,
                                              const float* __restrict__ b2,
                                              ushort_t* __restrict__ Vbf,
                                              ushort_t* __restrict__ W2T,
                                              float* __restrict__ qpb,
                                              int conv_blocks) {
    __shared__ float smem[1280];
    int bid = blockIdx.x;
    const int tid = threadIdx.x;

    if (bid < conv_blocks) {  // values fp32 -> bf16
        size_t i = ((size_t)bid * 256 + tid) * 8;
        f32x4 a = *(const f32x4*)(values + i);
        f32x4 b = *(const f32x4*)(values + i + 4);
        uint4 p;
        p.x = pk2(a[0], a[1]);
        p.y = pk2(a[2], a[3]);
        p.z = pk2(b[0], b[1]);
        p.w = pk2(b[2], b[3]);
        *(uint4*)(Vbf + i) = p;
        return;
    }
    bid -= conv_blocks;

    if (bid < TRANS_B) {  // W2 [D][U] -> W2T [U][D] bf16
        float(*tile)[33] = (float(*)[33])smem;
        int u0 = (bid & 31) * 32, d0 = (bid >> 5) * 32;
        int tx = tid & 31, ty = tid >> 5;
#pragma unroll
        for (int r = 0; r < 4; ++r)
            tile[ty + r * 8][tx] = W2[(size_t)(d0 + ty + r * 8) * U_ + (u0 + tx)];
        __syncthreads();
#pragma unroll
        for (int r = 0; r < 4; ++r)
            W2T[(size_t)(u0 + ty + r * 8) * D_ + (d0 + tx)] = f2bf(tile[tx][ty + r * 8]);
        return;
    }
    bid -= TRANS_B;

    // qproj: qpb[b][u] = query[b]@W1[:,u] + b1[u] + b2[u]
    const int b = bid >> 4, uc = bid & 15;
    float* qs = smem;          // [1024]
    float* red = smem + 1024;  // [256]
    for (int i = tid; i < D_; i += 256) qs[i] = query[b * D_ + i];
    __syncthreads();
    const int ul = tid & 63, ds = tid >> 6;
    const int u = uc * 64 + ul;
    float acc = 0.f;
#pragma unroll 8
    for (int d = ds * 256; d < ds * 256 + 256; ++d)
        acc += qs[d] * W1[(size_t)d * U_ + u];
    red[tid] = acc;
    __syncthreads();
    if (tid < 64) {
        int uu = uc * 64 + tid;
        qpb[b * U_ + uu] = red[tid] + red[tid + 64] + red[tid + 128] + red[tid + 192] +
                           b1[uu] + b2[uu];
    }
}

// ---------------- kernel 2: fused GEMM + tanh + Wv-dot (round-3) -----------
#define BM 128
#define BN 128
#define BK 64

__global__ __launch_bounds__(256) void k_score_gemm(const ushort_t* __restrict__ Vbf,
                                                    const ushort_t* __restrict__ W2T,
                                                    const float* __restrict__ qpb,
                                                    const float* __restrict__ Wv,
                                                    float* __restrict__ scores_partial) {
    __shared__ ushort_t As[BM * BK];  // 16 KB, swizzled: pos = chunk ^ (row&7)
    __shared__ ushort_t Bs[BN * BK];  // 16 KB
    __shared__ float sScore[BM];

    const int tid = threadIdx.x;
    const int lane = tid & 63;
    const int w = tid >> 6;
    const int wm = w >> 1, wn = w & 1;

    // XCD-grouped order: all 8 n-blocks of an m-tile land on one XCD
    const int g = blockIdx.x;
    const int mt = ((g >> 6) << 3) | (g & 7);
    const int nt = (g >> 3) & 7;
    const int m0 = mt * BM, n0 = nt * BN;

    if (tid < BM) sScore[tid] = 0.f;

    f32x4 acc[4][4];
#pragma unroll
    for (int i = 0; i < 4; ++i)
#pragma unroll
        for (int j = 0; j < 4; ++j) acc[i][j] = (f32x4){0.f, 0.f, 0.f, 0.f};

    const int lr = lane >> 3;            // 0..7
    const int c = (lane & 7) ^ lr;       // swizzled source chunk
    const ushort_t* aBase = Vbf + (size_t)(m0 + w * 8 + lr) * D_ + c * 8;
    const ushort_t* bBase = W2T + (size_t)(n0 + w * 8 + lr) * D_ + c * 8;

    const int quad = lane >> 4;
    const int l15 = lane & 15;
    const int l7 = l15 & 7;

    for (int k0 = 0; k0 < D_; k0 += BK) {
#pragma unroll
        for (int i = 0; i < 4; ++i) {
            __builtin_amdgcn_global_load_lds(
                (const GLOBAL_AS void*)(aBase + k0 + (size_t)i * 32 * D_),
                (LDS_AS void*)(As + i * 2048 + w * 512), 16, 0, 0);
        }
#pragma unroll
        for (int i = 0; i < 4; ++i) {
            __builtin_amdgcn_global_load_lds(
                (const GLOBAL_AS void*)(bBase + k0 + (size_t)i * 32 * D_),
                (LDS_AS void*)(Bs + i * 2048 + w * 512), 16, 0, 0);
        }
        __syncthreads();
#pragma unroll
        for (int kk = 0; kk < BK; kk += 32) {
            bf16x8 af[4], bfr[4];
            const int cb = kk >> 3;  // 0 or 4
#pragma unroll
            for (int i = 0; i < 4; ++i) {
                int r = wm * 64 + i * 16 + l15;
                af[i] = *(const bf16x8*)(As + (r << 6) + ((((quad + cb) ^ l7)) << 3));
            }
#pragma unroll
            for (int j = 0; j < 4; ++j) {
                int r = wn * 64 + j * 16 + l15;
                bfr[j] = *(const bf16x8*)(Bs + (r << 6) + ((((quad + cb) ^ l7)) << 3));
            }
#pragma unroll
            for (int i = 0; i < 4; ++i)
#pragma unroll
                for (int j = 0; j < 4; ++j)
                    acc[i][j] = __builtin_amdgcn_mfma_f32_16x16x32_bf16(
                        af[i], bfr[j], acc[i][j], 0, 0, 0);
        }
        __syncthreads();
    }

    // epilogue: C row = wm*64+i*16+quad*4+r, col(u) = n0+wn*64+j*16+l15
    const int b = m0 >> 11;
    const float* qp = qpb + b * U_;
    float qv[4], wv[4];
#pragma unroll
    for (int j = 0; j < 4; ++j) {
        int u = n0 + wn * 64 + j * 16 + l15;
        qv[j] = qp[u];
        wv[j] = Wv[u];
    }
#pragma unroll
    for (int i = 0; i < 4; ++i) {
#pragma unroll
        for (int r = 0; r < 4; ++r) {
            float s = 0.f;
#pragma unroll
            for (int j = 0; j < 4; ++j) s += fast_tanh(acc[i][j][r] + qv[j]) * wv[j];
            s += __shfl_xor(s, 1);
            s += __shfl_xor(s, 2);
            s += __shfl_xor(s, 4);
            s += __shfl_xor(s, 8);
            if (l15 == 0) atomicAdd(&sScore[wm * 64 + i * 16 + quad * 4 + r], s);
        }
    }
    __syncthreads();
    if (tid < BM) scores_partial[(size_t)(m0 + tid) * 8 + nt] = sScore[tid];
}

// ------- kernel 2b (fallback, ws too small): fp32-A in-kernel convert ------
__global__ __launch_bounds__(256) void k_score_gemm_f32(const float* __restrict__ values,
                                                        const ushort_t* __restrict__ W2T,
                                                        const float* __restrict__ qpb,
                                                        const float* __restrict__ Wv,
                                                        float* __restrict__ scores_partial) {
    __shared__ ushort_t As[BM * BK];
    __shared__ ushort_t Bs[BN * BK];
    __shared__ float sScore[BM];

    const int tid = threadIdx.x;
    const int lane = tid & 63;
    const int w = tid >> 6;
    const int wm = w >> 1, wn = w & 1;
    const int n0 = blockIdx.x * BN;
    const int m0 = blockIdx.y * BM;

    if (tid < BM) sScore[tid] = 0.f;

    f32x4 acc[4][4];
#pragma unroll
    for (int i = 0; i < 4; ++i)
#pragma unroll
        for (int j = 0; j < 4; ++j) acc[i][j] = (f32x4){0.f, 0.f, 0.f, 0.f};

    const int rr = tid >> 4;
    const int cc = tid & 15;
    const float* aSrc = values + (size_t)(m0 + rr) * D_ + cc * 4;
    ushort_t* aDst = As + rr * BK + cc * 4;

    const int mB = lane >> 3;
    const int kB = (lane & 7) * 8;
    const ushort_t* bBase = W2T + (size_t)(n0 + w * 8 + mB) * D_ + kB;

    const int quad = lane >> 4;
    const int l15 = lane & 15;

    for (int k0 = 0; k0 < D_; k0 += BK) {
#pragma unroll
        for (int i = 0; i < 4; ++i) {
            __builtin_amdgcn_global_load_lds(
                (const GLOBAL_AS void*)(bBase + k0 + (size_t)i * 32 * D_),
                (LDS_AS void*)(Bs + i * 2048 + w * 512), 16, 0, 0);
        }
#pragma unroll
        for (int i = 0; i < 8; ++i) {
            f32x4 v = *(const f32x4*)(aSrc + k0 + (size_t)i * 16 * D_);
            uint2 p;
            p.x = pk2(v[0], v[1]);
            p.y = pk2(v[2], v[3]);
            *(uint2*)(aDst + i * 16 * BK) = p;
        }
        __syncthreads();
#pragma unroll
        for (int kk = 0; kk < BK; kk += 32) {
            bf16x8 af[4], bfr[4];
            const int col = kk + quad * 8;
#pragma unroll
            for (int i = 0; i < 4; ++i)
                af[i] = *(const bf16x8*)(As + (wm * 64 + i * 16 + l15) * BK + col);
#pragma unroll
            for (int j = 0; j < 4; ++j)
                bfr[j] = *(const bf16x8*)(Bs + (wn * 64 + j * 16 + l15) * BK + col);
#pragma unroll
            for (int i = 0; i < 4; ++i)
#pragma unroll
                for (int j = 0; j < 4; ++j)
                    acc[i][j] = __builtin_amdgcn_mfma_f32_16x16x32_bf16(
                        af[i], bfr[j], acc[i][j], 0, 0, 0);
        }
        __syncthreads();
    }

    const int b = m0 >> 11;
    const float* qp = qpb + b * U_;
    float qv[4], wv[4];
#pragma unroll
    for (int j = 0; j < 4; ++j) {
        int u = n0 + wn * 64 + j * 16 + l15;
        qv[j] = qp[u];
        wv[j] = Wv[u];
    }
#pragma unroll
    for (int i = 0; i < 4; ++i) {
#pragma unroll
        for (int r = 0; r < 4; ++r) {
            float s = 0.f;
#pragma unroll
            for (int j = 0; j < 4; ++j) s += fast_tanh(acc[i][j][r] + qv[j]) * wv[j];
            s += __shfl_xor(s, 1);
            s += __shfl_xor(s, 2);
            s += __shfl_xor(s, 4);
            s += __shfl_xor(s, 8);
            if (l15 == 0) atomicAdd(&sScore[wm * 64 + i * 16 + quad * 4 + r], s);
        }
    }
    __syncthreads();
    if (tid < BM) scores_partial[(size_t)(m0 + tid) * 8 + blockIdx.x] = sScore[tid];
}

// ---------------- kernel 3: softmax over T per batch -----------------------
__global__ __launch_bounds__(256) void k_softmax(const float* __restrict__ scores_partial,
                                                 const float* __restrict__ bv,
                                                 float* __restrict__ w_f,
                                                 float* __restrict__ out_w) {
    const int b = blockIdx.x;
    __shared__ float s[T_];
    __shared__ float red[4];
    const int tid = threadIdx.x;
    const float bvf = bv[0];

    float lmax = -1e30f;
    for (int t = tid; t < T_; t += 256) {
        const float* p = scores_partial + (size_t)(b * T_ + t) * 8;
        float sc = ((p[0] + p[1]) + (p[2] + p[3])) + ((p[4] + p[5]) + (p[6] + p[7])) + bvf;
        s[t] = sc;
        lmax = fmaxf(lmax, sc);
    }
    for (int off = 32; off; off >>= 1) lmax = fmaxf(lmax, __shfl_xor(lmax, off));
    if ((tid & 63) == 0) red[tid >> 6] = lmax;
    __syncthreads();
    const float gmax = fmaxf(fmaxf(red[0], red[1]), fmaxf(red[2], red[3]));

    float lsum = 0.f;
    for (int t = tid; t < T_; t += 256) {
        float e = __expf(s[t] - gmax);
        s[t] = e;
        lsum += e;
    }
    for (int off = 32; off; off >>= 1) lsum += __shfl_xor(lsum, off);
    __syncthreads();
    if ((tid & 63) == 0) red[tid >> 6] = lsum;
    __syncthreads();
    const float ginv = 1.f / ((red[0] + red[1]) + (red[2] + red[3]));

    for (int t = tid; t < T_; t += 256) {
        float wgt = s[t] * ginv;
        w_f[b * T_ + t] = wgt;
        out_w[b * T_ + t] = wgt;
    }
}

// -------- kernel 4: ctx partials (bf16), atomic finish into out_ctx --------
__global__ __launch_bounds__(256) void k_ctx_bf(const ushort_t* __restrict__ Vbf,
                                                const float* __restrict__ w_f,
                                                float* __restrict__ out_ctx) {
    const int tc = blockIdx.x;  // 0..15
    const int b = blockIdx.y;   // 0..31
    const int tid = threadIdx.x;
    __shared__ float wls[128];
    __shared__ float racc[128 * 8];
    if (tid < 128) wls[tid] = w_f[b * T_ + tc * 128 + tid];
    __syncthreads();

    const int dg = tid & 127, th = tid >> 7;
    const int d0 = dg * 8;
    float acc[8] = {0.f, 0.f, 0.f, 0.f, 0.f, 0.f, 0.f, 0.f};
    const ushort_t* base = Vbf + (size_t)(b * T_ + tc * 128) * D_ + d0;
    for (int tt = th; tt < 128; tt += 2) {
        const float wgt = wls[tt];
        bf16x8 v = *(const bf16x8*)(base + (size_t)tt * D_);
#pragma unroll
        for (int i = 0; i < 8; ++i) acc[i] += wgt * bf2f((ushort_t)v[i]);
    }
    if (th == 1) {
#pragma unroll
        for (int i = 0; i < 8; ++i) racc[dg * 8 + i] = acc[i];
    }
    __syncthreads();
    if (th == 0) {
        float* out = out_ctx + b * D_ + d0;
#pragma unroll
        for (int i = 0; i < 8; ++i) atomicAdd(&out[i], acc[i] + racc[dg * 8 + i]);
    }
}

// -------- kernel 4b (fallback): ctx partials (fp32), atomic finish ---------
__global__ __launch_bounds__(256) void k_ctx_f32(const float* __restrict__ values,
                                                 const float* __restrict__ w_f,
                                                 float* __restrict__ out_ctx) {
    const int tc = blockIdx.x;  // 0..15
    const int b = blockIdx.y;
    const int tid = threadIdx.x;
    __shared__ float wls[128];
    if (tid < 128) wls[tid] = w_f[b * T_ + tc * 128 + tid];
    __syncthreads();

    f32x4 acc = (f32x4){0.f, 0.f, 0.f, 0.f};
    const float* base = values + (size_t)(b * T_ + tc * 128) * D_ + tid * 4;
#pragma unroll 4
    for (int tt = 0; tt < 128; ++tt)
        acc += wls[tt] * *(const f32x4*)(base + (size_t)tt * D_);
    float* out = out_ctx + b * D_ + tid * 4;
    atomicAdd(&out[0], acc[0]);
    atomicAdd(&out[1], acc[1]);
    atomicAdd(&out[2], acc[2]);
    atomicAdd(&out[3], acc[3]);
}

// ---------------------------------------------------------------------------
extern "C" void kernel_launch(void* const* d_in, const int* in_sizes, int n_in,
                              void* d_out, int out_size, void* d_ws, size_t ws_size,
                              hipStream_t stream) {
    const float* query  = (const float*)d_in[0];
    const float* values = (const float*)d_in[1];
    const float* W1     = (const float*)d_in[2];
    const float* b1     = (const float*)d_in[3];
    const float* W2     = (const float*)d_in[4];
    const float* b2     = (const float*)d_in[5];
    const float* Wv     = (const float*)d_in[6];
    const float* bv     = (const float*)d_in[7];

    float* out_ctx = (float*)d_out;          // [32*1024]
    float* out_w   = out_ctx + B_ * D_;      // [32*2048]

    char* ws = (char*)d_ws;
    const size_t OFF_W2T = 0;                 // 2 MB bf16
    const size_t OFF_QPB = 0x200000;          // 128 KB
    const size_t OFF_SP  = 0x220000;          // 2 MB
    const size_t OFF_WF  = 0x420000;          // 256 KB
    const size_t OFF_VBF = 0x460000;          // 128 MB bf16 values
    const size_t NEED    = OFF_VBF + (size_t)M_ * D_ * sizeof(ushort_t);

    ushort_t* W2T            = (ushort_t*)(ws + OFF_W2T);
    float*    qpb            = (float*)(ws + OFF_QPB);
    float*    scores_partial = (float*)(ws + OFF_SP);
    float*    w_f            = (float*)(ws + OFF_WF);
    ushort_t* Vbf            = (ushort_t*)(ws + OFF_VBF);

    // out_ctx accumulated via atomics; zero it first (graph-capture legal)
    hipMemsetAsync(out_ctx, 0, (size_t)B_ * D_ * sizeof(float), stream);

    if (ws_size >= NEED) {
        k_prep<<<dim3(CONV_B + TRANS_B + QPROJ_B), 256, 0, stream>>>(
            values, W2, query, W1, b1, b2, Vbf, W2T, qpb, CONV_B);
        k_score_gemm<<<dim3((M_ / BM) * (U_ / BN)), 256, 0, stream>>>(
            Vbf, W2T, qpb, Wv, scores_partial);
        k_softmax<<<dim3(B_), 256, 0, stream>>>(scores_partial, bv, w_f, out_w);
        k_ctx_bf<<<dim3(16, B_), 256, 0, stream>>>(Vbf, w_f, out_ctx);
    } else {
        k_prep<<<dim3(TRANS_B + QPROJ_B), 256, 0, stream>>>(
            values, W2, query, W1, b1, b2, Vbf, W2T, qpb, 0);
        k_score_gemm_f32<<<dim3(U_ / BN, M_ / BM), 256, 0, stream>>>(
            values, W2T, qpb, Wv, scores_partial);
        k_softmax<<<dim3(B_), 256, 0, stream>>>(scores_partial, bv, w_f, out_w);
        k_ctx_f32<<<dim3(16, B_), 256, 0, stream>>>(values, w_f, out_ctx);
    }

    (void)in_sizes; (void)n_in; (void)out_size; (void)ws_size;
}

// Round 6
// 580.628 us; speedup vs baseline: 1.5428x; 1.0846x over previous
//
#include <hip/hip_runtime.h>
#include <hip/hip_bf16.h>
#include <stdint.h>

// ---------------------------------------------------------------------------
// Bahdanau additive attention, B=32, T=2048, D=U=1024. fp32 in/out.
// Outputs (fp32, flat): ctx [32*1024] then weights [32*2048].
// Round 6: GEMM reads fp32 values directly (in-staging fp32->bf16 convert,
// XOR-swizzled LDS, XCD-grouped block order). No separate convert pass.
// ---------------------------------------------------------------------------

typedef unsigned short ushort_t;
typedef short bf16x8 __attribute__((ext_vector_type(8)));
typedef float f32x4 __attribute__((ext_vector_type(4)));

#define GLOBAL_AS __attribute__((address_space(1)))
#define LDS_AS    __attribute__((address_space(3)))

__device__ __forceinline__ ushort_t f2bf(float f) {
    union { float f; unsigned int u; } v;
    v.f = f;
    unsigned int u = v.u;
    unsigned int r = u + 0x7FFFu + ((u >> 16) & 1u);  // RNE
    return (ushort_t)(r >> 16);
}
__device__ __forceinline__ unsigned int pk2(float a, float b) {
    union { __hip_bfloat162 h; unsigned int u; } c;
    c.h = __float22bfloat162_rn(make_float2(a, b));  // v_cvt_pk_bf16_f32
    return c.u;
}
__device__ __forceinline__ float fast_tanh(float x) {
    float ax = __builtin_fabsf(x);
    float e = __expf(-2.0f * ax);
    float t = (1.0f - e) * __builtin_amdgcn_rcpf(1.0f + e);
    return __builtin_copysignf(t, x);
}

static constexpr int B_ = 32, T_ = 2048, D_ = 1024, U_ = 1024;
static constexpr int M_ = B_ * T_;  // 65536
static constexpr int TRANS_B = 1024;
static constexpr int QPROJ_B = 512;

// ---------------- kernel 1: fused prep (transpose | qproj) -----------------
__global__ __launch_bounds__(256) void k_prep(const float* __restrict__ W2,
                                              const float* __restrict__ query,
                                              const float* __restrict__ W1,
                                              const float* __restrict__ b1,
                                              const float* __restrict__ b2,
                                              ushort_t* __restrict__ W2T,
                                              float* __restrict__ qpb) {
    __shared__ float smem[1280];
    int bid = blockIdx.x;
    const int tid = threadIdx.x;

    if (bid < TRANS_B) {  // W2 [D][U] -> W2T [U][D] bf16
        float(*tile)[33] = (float(*)[33])smem;
        int u0 = (bid & 31) * 32, d0 = (bid >> 5) * 32;
        int tx = tid & 31, ty = tid >> 5;
#pragma unroll
        for (int r = 0; r < 4; ++r)
            tile[ty + r * 8][tx] = W2[(size_t)(d0 + ty + r * 8) * U_ + (u0 + tx)];
        __syncthreads();
#pragma unroll
        for (int r = 0; r < 4; ++r)
            W2T[(size_t)(u0 + ty + r * 8) * D_ + (d0 + tx)] = f2bf(tile[tx][ty + r * 8]);
        return;
    }
    bid -= TRANS_B;

    // qproj: qpb[b][u] = query[b]@W1[:,u] + b1[u] + b2[u]
    const int b = bid >> 4, uc = bid & 15;
    float* qs = smem;          // [1024]
    float* red = smem + 1024;  // [256]
    for (int i = tid; i < D_; i += 256) qs[i] = query[b * D_ + i];
    __syncthreads();
    const int ul = tid & 63, ds = tid >> 6;
    const int u = uc * 64 + ul;
    float acc = 0.f;
#pragma unroll 8
    for (int d = ds * 256; d < ds * 256 + 256; ++d)
        acc += qs[d] * W1[(size_t)d * U_ + u];
    red[tid] = acc;
    __syncthreads();
    if (tid < 64) {
        int uu = uc * 64 + tid;
        qpb[b * U_ + uu] = red[tid] + red[tid + 64] + red[tid + 128] + red[tid + 192] +
                           b1[uu] + b2[uu];
    }
}

// ---------------- kernel 2: fused GEMM + tanh + Wv-dot (fp32 A) ------------
// A staged with in-flight fp32->bf16 convert; both tiles XOR-swizzled at 16B
// granularity: LDS position p holds source chunk p ^ (row&7).
#define BM 128
#define BN 128
#define BK 64

__global__ __launch_bounds__(256) void k_score_gemm(const float* __restrict__ values,
                                                    const ushort_t* __restrict__ W2T,
                                                    const float* __restrict__ qpb,
                                                    const float* __restrict__ Wv,
                                                    float* __restrict__ scores_partial) {
    __shared__ ushort_t As[BM * BK];  // 16 KB
    __shared__ ushort_t Bs[BN * BK];  // 16 KB
    __shared__ float sScore[BM];

    const int tid = threadIdx.x;
    const int lane = tid & 63;
    const int w = tid >> 6;
    const int wm = w >> 1, wn = w & 1;

    // XCD-grouped order: the 8 n-blocks of an m-tile get adjacent block ids
    const int g = blockIdx.x;
    const int mt = ((g >> 6) << 3) | (g & 7);
    const int nt = (g >> 3) & 7;
    const int m0 = mt * BM, n0 = nt * BN;

    if (tid < BM) sScore[tid] = 0.f;

    f32x4 acc[4][4];
#pragma unroll
    for (int i = 0; i < 4; ++i)
#pragma unroll
        for (int j = 0; j < 4; ++j) acc[i][j] = (f32x4){0.f, 0.f, 0.f, 0.f};

    // ---- A staging map: iteration i covers rows i*32 + (tid>>3) ----
    const int rA = tid >> 3;       // 0..31
    const int cA = tid & 7;        // source chunk (8 fp32)
    const int pA = cA ^ (rA & 7);  // swizzled LDS position
    const float* aSrc = values + (size_t)(m0 + rA) * D_ + cA * 8;
    ushort_t* aDst = As + rA * BK + pA * 8;

    // ---- B staging map (global_load_lds, source-side swizzle) ----
    const int lr = lane >> 3;
    const int cB = (lane & 7) ^ lr;
    const ushort_t* bBase = W2T + (size_t)(n0 + w * 8 + lr) * D_ + cB * 8;

    const int quad = lane >> 4;
    const int l15 = lane & 15;
    const int l7 = l15 & 7;

    for (int k0 = 0; k0 < D_; k0 += BK) {
        // B first: DMA runs while A converts through VALU
#pragma unroll
        for (int i = 0; i < 4; ++i) {
            __builtin_amdgcn_global_load_lds(
                (const GLOBAL_AS void*)(bBase + k0 + (size_t)i * 32 * D_),
                (LDS_AS void*)(Bs + i * 2048 + w * 512), 16, 0, 0);
        }
#pragma unroll
        for (int i = 0; i < 4; ++i) {
            f32x4 v0 = *(const f32x4*)(aSrc + k0 + (size_t)i * 32 * D_);
            f32x4 v1 = *(const f32x4*)(aSrc + k0 + (size_t)i * 32 * D_ + 4);
            uint4 p;
            p.x = pk2(v0[0], v0[1]);
            p.y = pk2(v0[2], v0[3]);
            p.z = pk2(v1[0], v1[1]);
            p.w = pk2(v1[2], v1[3]);
            *(uint4*)(aDst + i * 32 * BK) = p;
        }
        __syncthreads();
#pragma unroll
        for (int kk = 0; kk < BK; kk += 32) {
            bf16x8 af[4], bfr[4];
            const int cb = kk >> 3;  // 0 or 4
#pragma unroll
            for (int i = 0; i < 4; ++i) {
                int r = wm * 64 + i * 16 + l15;
                af[i] = *(const bf16x8*)(As + (r << 6) + (((quad + cb) ^ l7) << 3));
            }
#pragma unroll
            for (int j = 0; j < 4; ++j) {
                int r = wn * 64 + j * 16 + l15;
                bfr[j] = *(const bf16x8*)(Bs + (r << 6) + (((quad + cb) ^ l7) << 3));
            }
#pragma unroll
            for (int i = 0; i < 4; ++i)
#pragma unroll
                for (int j = 0; j < 4; ++j)
                    acc[i][j] = __builtin_amdgcn_mfma_f32_16x16x32_bf16(
                        af[i], bfr[j], acc[i][j], 0, 0, 0);
        }
        __syncthreads();
    }

    // epilogue: C row = wm*64+i*16+quad*4+r, col(u) = n0+wn*64+j*16+l15
    const int b = m0 >> 11;
    const float* qp = qpb + b * U_;
    float qv[4], wv[4];
#pragma unroll
    for (int j = 0; j < 4; ++j) {
        int u = n0 + wn * 64 + j * 16 + l15;
        qv[j] = qp[u];
        wv[j] = Wv[u];
    }
#pragma unroll
    for (int i = 0; i < 4; ++i) {
#pragma unroll
        for (int r = 0; r < 4; ++r) {
            float s = 0.f;
#pragma unroll
            for (int j = 0; j < 4; ++j) s += fast_tanh(acc[i][j][r] + qv[j]) * wv[j];
            s += __shfl_xor(s, 1);
            s += __shfl_xor(s, 2);
            s += __shfl_xor(s, 4);
            s += __shfl_xor(s, 8);
            if (l15 == 0) atomicAdd(&sScore[wm * 64 + i * 16 + quad * 4 + r], s);
        }
    }
    __syncthreads();
    if (tid < BM) scores_partial[(size_t)(m0 + tid) * 8 + nt] = sScore[tid];
}

// ---------------- kernel 3: softmax over T per batch -----------------------
__global__ __launch_bounds__(256) void k_softmax(const float* __restrict__ scores_partial,
                                                 const float* __restrict__ bv,
                                                 float* __restrict__ w_f,
                                                 float* __restrict__ out_w) {
    const int b = blockIdx.x;
    __shared__ float s[T_];
    __shared__ float red[4];
    const int tid = threadIdx.x;
    const float bvf = bv[0];

    float lmax = -1e30f;
    for (int t = tid; t < T_; t += 256) {
        const float* p = scores_partial + (size_t)(b * T_ + t) * 8;
        float sc = ((p[0] + p[1]) + (p[2] + p[3])) + ((p[4] + p[5]) + (p[6] + p[7])) + bvf;
        s[t] = sc;
        lmax = fmaxf(lmax, sc);
    }
    for (int off = 32; off; off >>= 1) lmax = fmaxf(lmax, __shfl_xor(lmax, off));
    if ((tid & 63) == 0) red[tid >> 6] = lmax;
    __syncthreads();
    const float gmax = fmaxf(fmaxf(red[0], red[1]), fmaxf(red[2], red[3]));

    float lsum = 0.f;
    for (int t = tid; t < T_; t += 256) {
        float e = __expf(s[t] - gmax);
        s[t] = e;
        lsum += e;
    }
    for (int off = 32; off; off >>= 1) lsum += __shfl_xor(lsum, off);
    __syncthreads();
    if ((tid & 63) == 0) red[tid >> 6] = lsum;
    __syncthreads();
    const float ginv = 1.f / ((red[0] + red[1]) + (red[2] + red[3]));

    for (int t = tid; t < T_; t += 256) {
        float wgt = s[t] * ginv;
        w_f[b * T_ + t] = wgt;
        out_w[b * T_ + t] = wgt;
    }
}

// -------- kernel 4: ctx partials (fp32), atomic finish into out_ctx --------
__global__ __launch_bounds__(256) void k_ctx(const float* __restrict__ values,
                                             const float* __restrict__ w_f,
                                             float* __restrict__ out_ctx) {
    const int tc = blockIdx.x;  // 0..15
    const int b = blockIdx.y;   // 0..31
    const int tid = threadIdx.x;
    __shared__ float wls[128];
    if (tid < 128) wls[tid] = w_f[b * T_ + tc * 128 + tid];
    __syncthreads();

    f32x4 acc = (f32x4){0.f, 0.f, 0.f, 0.f};
    const float* base = values + (size_t)(b * T_ + tc * 128) * D_ + tid * 4;
#pragma unroll 4
    for (int tt = 0; tt < 128; ++tt)
        acc += wls[tt] * *(const f32x4*)(base + (size_t)tt * D_);
    float* out = out_ctx + b * D_ + tid * 4;
    atomicAdd(&out[0], acc[0]);
    atomicAdd(&out[1], acc[1]);
    atomicAdd(&out[2], acc[2]);
    atomicAdd(&out[3], acc[3]);
}

// ---------------------------------------------------------------------------
extern "C" void kernel_launch(void* const* d_in, const int* in_sizes, int n_in,
                              void* d_out, int out_size, void* d_ws, size_t ws_size,
                              hipStream_t stream) {
    const float* query  = (const float*)d_in[0];
    const float* values = (const float*)d_in[1];
    const float* W1     = (const float*)d_in[2];
    const float* b1     = (const float*)d_in[3];
    const float* W2     = (const float*)d_in[4];
    const float* b2     = (const float*)d_in[5];
    const float* Wv     = (const float*)d_in[6];
    const float* bv     = (const float*)d_in[7];

    float* out_ctx = (float*)d_out;          // [32*1024]
    float* out_w   = out_ctx + B_ * D_;      // [32*2048]

    char* ws = (char*)d_ws;
    const size_t OFF_W2T = 0;                 // 2 MB bf16
    const size_t OFF_QPB = 0x200000;          // 128 KB
    const size_t OFF_SP  = 0x220000;          // 2 MB
    const size_t OFF_WF  = 0x420000;          // 256 KB

    ushort_t* W2T            = (ushort_t*)(ws + OFF_W2T);
    float*    qpb            = (float*)(ws + OFF_QPB);
    float*    scores_partial = (float*)(ws + OFF_SP);
    float*    w_f            = (float*)(ws + OFF_WF);

    // out_ctx accumulated via atomics; zero it first (graph-capture legal)
    hipMemsetAsync(out_ctx, 0, (size_t)B_ * D_ * sizeof(float), stream);

    k_prep<<<dim3(TRANS_B + QPROJ_B), 256, 0, stream>>>(W2, query, W1, b1, b2, W2T, qpb);
    k_score_gemm<<<dim3((M_ / BM) * (U_ / BN)), 256, 0, stream>>>(
        values, W2T, qpb, Wv, scores_partial);
    k_softmax<<<dim3(B_), 256, 0, stream>>>(scores_partial, bv, w_f, out_w);
    k_ctx<<<dim3(16, B_), 256, 0, stream>>>(values, w_f, out_ctx);

    (void)in_sizes; (void)n_in; (void)out_size; (void)ws_size;
}